// Round 15
// baseline (677.792 us; speedup 1.0000x reference)
//
#include <hip/hip_runtime.h>
#include <cstdint>
#include <cstddef>

typedef __attribute__((ext_vector_type(8))) short short8;
typedef __attribute__((ext_vector_type(4))) float f32x4;

#define DEV static __device__ __forceinline__

DEV float bf2f(short s) {
  union { unsigned u; float f; } c; c.u = ((unsigned)(unsigned short)s) << 16; return c.f;
}
DEV short f2bf(float f) {
  union { float f; unsigned u; } c; c.f = f;
  unsigned r = c.u + 0x7FFFu + ((c.u >> 16) & 1u);
  return (short)(r >> 16);
}

DEV void gload_lds16(const void* g, void* l) {
  __builtin_amdgcn_global_load_lds((const __attribute__((address_space(1))) void*)g,
                                   (__attribute__((address_space(3))) void*)l, 16, 0, 0);
}

// 16-lane-row reductions via DPP (VALU pipe, not DS): xor1, xor2, half-mirror, mirror
#define DPP_STEP(v, ctrl, OP) { \
  int _t = __builtin_amdgcn_update_dpp( \
      __builtin_bit_cast(int, v), __builtin_bit_cast(int, v), ctrl, 0xF, 0xF, true); \
  v = OP(v, __builtin_bit_cast(float, _t)); }
DEV float row16_max(float v) {
  DPP_STEP(v, 0xB1, fmaxf)   // quad_perm [1,0,3,2] = xor1
  DPP_STEP(v, 0x4E, fmaxf)   // quad_perm [2,3,0,1] = xor2
  DPP_STEP(v, 0x141, fmaxf)  // row_half_mirror
  DPP_STEP(v, 0x140, fmaxf)  // row_mirror
  return v;
}
DEV float fadd2(float a, float b) { return a + b; }
DEV float row16_sum(float v) {
  DPP_STEP(v, 0xB1, fadd2)
  DPP_STEP(v, 0x4E, fadd2)
  DPP_STEP(v, 0x141, fadd2)
  DPP_STEP(v, 0x140, fadd2)
  return v;
}

// ---------------- fp32 -> bf16 convert, 8 elems/thread ----------------
__global__ __launch_bounds__(256) void cvt_bf16(const float* __restrict__ s,
                                                short* __restrict__ d, int n8) {
  int i = blockIdx.x * 256 + threadIdx.x;
  if (i >= n8) return;
  const float4* sp = (const float4*)s + (size_t)i * 2;
  float4 a = sp[0], b = sp[1];
  short8 o;
  o[0] = f2bf(a.x); o[1] = f2bf(a.y); o[2] = f2bf(a.z); o[3] = f2bf(a.w);
  o[4] = f2bf(b.x); o[5] = f2bf(b.y); o[6] = f2bf(b.z); o[7] = f2bf(b.w);
  *((short8*)d + i) = o;
}

// ---------------- GEMM: C[m][n] = sum_k A[m][k] * W[n][k] (+bias) ----------------
// R15 DIAGNOSTIC: R13 structure + NREP internal reps (idempotent) so both
// GEMMs surface in rocprof top-5 with true rate counters. Divide dur by NREP.
// K-loop (R13): 256x128 tile, BK=64, 8 waves (4Mx2N; per-wave 64x64), TRIPLE-
// buffered LDS (3 x 48 KB). Top-of-tile vmcnt(6) -> 2 phases of {ds_read
// frags + issue 3 staging loads for t+2 -> barrier -> setprio(1) -> 16 MFMA
// -> setprio(0) -> barrier}. Counted vmcnt, never 0 mid-loop.
template<int MODE, int NREP>
__global__ __launch_bounds__(512) void gemm_bt(
    const short* __restrict__ A, const short* __restrict__ W,
    const float* __restrict__ biasA, const float* __restrict__ biasB,
    short* __restrict__ Oq, short* __restrict__ Ok, short* __restrict__ Ov,
    float* __restrict__ Of)
{
  __shared__ char SM[147456];  // slot s at s*49152: A [0,32K) + B [32K,48K)
  const int tid = threadIdx.x, w = tid >> 6, lane = tid & 63;
  const int lr = lane & 15, lg = lane >> 4;
  const int m0 = blockIdx.x * 256;
  int mat = 0, n0;
  const short* Wm;
  if (MODE == 0) { mat = blockIdx.y >> 3; n0 = (blockIdx.y & 7) * 128; Wm = W + (size_t)mat * 1048576; }
  else           { n0 = blockIdx.y * 128; Wm = W; }
  const int wr = (w >> 1) * 64, wc = (w & 1) * 64;   // wave tile: 64(M) x 64(N)

  const f32x4 fz = {0.f, 0.f, 0.f, 0.f};

  // stage one half (3 loads/thread: 2 A + 1 B) of K-tile t into slot.
  auto stageHalf = [&](int t, int slot, int half) {
    const size_t kb = (size_t)t * 128;           // 64 cols * 2B
    char* Ad = SM + slot * 49152;
    char* Bd = Ad + 32768;
    #pragma unroll
    for (int i = 0; i < 2; ++i) {
      const int idx2 = (half * 2 + i) * 512 + tid;         // 0..2047
      const int r = idx2 >> 3, c16 = idx2 & 7;
      const int cs = (c16 ^ (r & 7)) << 4;
      gload_lds16((const char*)A + (size_t)(m0 + r) * 2048 + kb + cs, Ad + idx2 * 16);
    }
    {
      const int idx2 = half * 512 + tid;                   // 0..1023
      const int r = idx2 >> 3, c16 = idx2 & 7;
      const int cs = (c16 ^ (r & 7)) << 4;
      gload_lds16((const char*)Wm + (size_t)(n0 + r) * 2048 + kb + cs, Bd + idx2 * 16);
    }
  };

  for (int rep = 0; rep < NREP; ++rep) {
    __syncthreads();   // previous rep's epilogue (TB aliases SM) fully done

    f32x4 acc[4][4];
    #pragma unroll
    for (int i = 0; i < 4; ++i)
      #pragma unroll
      for (int j = 0; j < 4; ++j) acc[i][j] = fz;

    // prologue: tiles 0 (slot 0) and 1 (slot 1) fully issued
    stageHalf(0, 0, 0); stageHalf(0, 0, 1);
    stageHalf(1, 1, 0); stageHalf(1, 1, 1);

    int slot = 0;
    for (int t = 0; t < 16; ++t) {
      if (t < 15) asm volatile("s_waitcnt vmcnt(6)" ::: "memory");
      else        asm volatile("s_waitcnt vmcnt(0)" ::: "memory");
      __builtin_amdgcn_s_barrier();

      const char* Asl = SM + slot * 49152;
      const char* Bsl = Asl + 32768;
      const int slot2 = (slot == 0) ? 2 : slot - 1;        // (t+2)%3

      #pragma unroll
      for (int ks = 0; ks < 2; ++ks) {
        short8 af[4], bf[4];
        #pragma unroll
        for (int nr = 0; nr < 4; ++nr) {
          const int row = wc + nr * 16 + lr;
          bf[nr] = *(const short8*)(Bsl + row * 128 + ((ks * 64 + lg * 16) ^ ((row & 7) << 4)));
        }
        #pragma unroll
        for (int mr = 0; mr < 4; ++mr) {
          const int row = wr + mr * 16 + lr;
          af[mr] = *(const short8*)(Asl + row * 128 + ((ks * 64 + lg * 16) ^ ((row & 7) << 4)));
        }
        if (t < 14) stageHalf(t + 2, slot2, ks);
        __builtin_amdgcn_s_barrier();
        __builtin_amdgcn_s_setprio(1);
        #pragma unroll
        for (int mr = 0; mr < 4; ++mr)
          #pragma unroll
          for (int nr = 0; nr < 4; ++nr)
            acc[mr][nr] = __builtin_amdgcn_mfma_f32_16x16x32_bf16(af[mr], bf[nr], acc[mr][nr], 0, 0, 0);
        __builtin_amdgcn_s_setprio(0);
        __builtin_amdgcn_s_barrier();
      }
      slot = (slot == 2) ? 0 : slot + 1;
    }

    if (MODE == 0 && mat == 2) {
      // V epilogue: per 64-col half h2, transpose 256m x 64n through TB,
      // store 64B-contiguous s-runs into VT[bh][dd][s].
      short* TB = (short*)SM;                    // 256*68*2 = 34816 B
      #pragma unroll
      for (int h2 = 0; h2 < 2; ++h2) {
        __syncthreads();
        if ((w & 1) == h2) {                     // 4 waves own this n-half
          #pragma unroll
          for (int mr = 0; mr < 4; ++mr)
            #pragma unroll
            for (int nr = 0; nr < 4; ++nr)
              #pragma unroll
              for (int r = 0; r < 4; ++r) {
                const int ml = wr + mr * 16 + lg * 4 + r;
                const int nl = nr * 16 + lr;
                TB[ml * 68 + nl] = f2bf(acc[mr][nr][r] + biasB[n0 + h2 * 64 + nl]);
              }
        }
        __syncthreads();
        const int hh = (n0 >> 6) + h2;           // global head
        const int dd = tid & 63, b = tid >> 6;   // 64 dd x 8 b = 512 threads
        short tmp[32];
        #pragma unroll
        for (int j = 0; j < 32; ++j) tmp[j] = TB[(j * 8 + b) * 68 + dd];
        const size_t base = (size_t)(b * 16 + hh) * 65536 + (size_t)dd * 1024 + (m0 >> 3);
        #pragma unroll
        for (int j = 0; j < 4; ++j)
          *(short8*)(Ov + base + j * 8) = *(short8*)(tmp + j * 8);
      }
    } else {
      #pragma unroll
      for (int mr = 0; mr < 4; ++mr)
      #pragma unroll
      for (int nr = 0; nr < 4; ++nr)
      #pragma unroll
      for (int r = 0; r < 4; ++r) {
        const int mrow = m0 + wr + mr * 16 + lg * 4 + r;   // C row = (l>>4)*4+r  [m89]
        const int ncol = n0 + wc + nr * 16 + lr;           // C col = l&15
        float v = acc[mr][nr][r];
        if (MODE == 0) {
          const int s = mrow >> 3, b = mrow & 7, h = ncol >> 6, dd = ncol & 63;
          const size_t base = (size_t)(b * 16 + h) * 65536;
          if (mat == 0)      Oq[base + (size_t)s * 64 + dd] = f2bf((v + biasA[ncol]) * 0.125f);
          else               Ok[base + (size_t)s * 64 + dd] = f2bf(v);
        } else {
          Of[(size_t)mrow * 1024 + ncol] = v + biasA[ncol];
        }
      }
    }
  } // rep
}

// ---------------- attention ----------------
// R7/R11 structure (best known): 8 waves / 128 q-rows per block, K/V LDS-staged
// with both-sides XOR swizzle, bias in register double-buffer, 1-iteration
// pipeline via counted vmcnt(18), DPP softmax.
DEV void stage_kv(const char* Kg, const char* Vg, int kt,
                  short* ksb, short* vsb, int tid) {
  const int L = tid * 16;            // 512 threads x 16B = 8 KB tile
  const int row = L >> 7, c = L & 127;
  const int cs = c ^ ((row & 7) << 4);
  gload_lds16(Kg + (size_t)kt * 8192 + row * 128 + cs, (char*)ksb + L);
  gload_lds16(Vg + (size_t)row * 2048 + (size_t)kt * 128 + cs, (char*)vsb + L);
}

__global__ __launch_bounds__(512) void attn_fwd(
    const short* __restrict__ Q, const short* __restrict__ K,
    const short* __restrict__ VT, const float* __restrict__ bias,
    short* __restrict__ AO)
{
  __shared__ short Ks[2][4096];     // [s=64][d=64] bf16, swizzled      (16 KB)
  __shared__ short Vs[2][4096];     // [d=64][s=64] bf16, swizzled      (16 KB)
  __shared__ short PL[8][16 * 72];  // per-wave P strip, padded         (18 KB)
  const int tid = threadIdx.x, w = tid >> 6, lane = tid & 63;
  const int lr = lane & 15, lg = lane >> 4;
  // XCD-chunked swizzle: XCD x gets heads [x*16,(x+1)*16); 8 blocks/head
  const int bid = blockIdx.x;
  const int L = (bid & 7) * 128 + (bid >> 3);
  const int bh = L >> 3, qb = L & 7;
  const int q0 = qb * 128 + w * 16;

  const char* Kg = (const char*)K  + ((size_t)bh << 17);
  const char* Vg = (const char*)VT + ((size_t)bh << 17);
  const short* Qh = Q + ((size_t)bh << 16);
  // per-lane bias base: row (q0+lg*4), col lr
  const float* Bw = bias + ((size_t)bh << 20) + (size_t)(q0 + lg * 4) * 1024 + lr;

  const short8 qf0 = *(const short8*)(Qh + (q0 + lr) * 64 + lg * 8);
  const short8 qf1 = *(const short8*)(Qh + (q0 + lr) * 64 + 32 + lg * 8);

  // swizzled read offsets: row-dependent key is (lr&7) for row = n*16+lr
  const int S = (lr & 7) << 4;
  const int off0 = (lg * 16) ^ S;
  const int off1 = (64 + lg * 16) ^ S;

  const f32x4 fz = {0.f, 0.f, 0.f, 0.f};
  f32x4 accO[4] = {fz, fz, fz, fz};
  float mrow[4] = {-3e30f, -3e30f, -3e30f, -3e30f};
  float ssum[4] = {0.f, 0.f, 0.f, 0.f};

  float bb0[4][4], bb1[4][4];
  #pragma unroll
  for (int n = 0; n < 4; ++n)
    #pragma unroll
    for (int r = 0; r < 4; ++r)
      bb0[n][r] = Bw[(size_t)r * 1024 + n * 16];
  stage_kv(Kg, Vg, 0, Ks[0], Vs[0], tid);
  asm volatile("s_waitcnt vmcnt(0)" ::: "memory");
  __builtin_amdgcn_s_barrier();

  auto body = [&](int kt, float (&bbc)[4][4], float (&bbn)[4][4]) {
    const int cur = kt & 1;
    if (kt < 15) {
      // bias prefetch for kt+1 into registers (dominant HBM stream)
      #pragma unroll
      for (int n = 0; n < 4; ++n)
        #pragma unroll
        for (int r = 0; r < 4; ++r)
          bbn[n][r] = Bw[(size_t)r * 1024 + (kt + 1) * 64 + n * 16];
      stage_kv(Kg, Vg, kt + 1, Ks[cur ^ 1], Vs[cur ^ 1], tid);
      __builtin_amdgcn_sched_barrier(0);   // pin prefetch issue before compute
      asm volatile("s_waitcnt vmcnt(18)" ::: "memory");  // drain tile kt (16 bias + 2 KV newer)
    } else {
      asm volatile("s_waitcnt vmcnt(0)" ::: "memory");
    }
    __builtin_amdgcn_s_barrier();   // buf[cur] complete for all waves

    // S = Q*K^T from swizzled Ks
    f32x4 s[4];
    #pragma unroll
    for (int n = 0; n < 4; ++n) {
      const char* kp = (const char*)Ks[cur] + (n * 16 + lr) * 128;
      short8 kf0 = *(const short8*)(kp + off0);
      short8 kf1 = *(const short8*)(kp + off1);
      f32x4 z = fz;
      z    = __builtin_amdgcn_mfma_f32_16x16x32_bf16(qf0, kf0, z, 0, 0, 0);
      s[n] = __builtin_amdgcn_mfma_f32_16x16x32_bf16(qf1, kf1, z, 0, 0, 0);
    }
    #pragma unroll
    for (int n = 0; n < 4; ++n)
      #pragma unroll
      for (int r = 0; r < 4; ++r) s[n][r] += bbc[n][r];

    // online softmax; 16-lane row reduce via DPP (VALU pipe)
    float sc[4];
    #pragma unroll
    for (int r = 0; r < 4; ++r) {
      float t = fmaxf(fmaxf(s[0][r], s[1][r]), fmaxf(s[2][r], s[3][r]));
      t = row16_max(t);
      float mn = fmaxf(mrow[r], t);
      sc[r] = __expf(mrow[r] - mn);
      mrow[r] = mn;
    }
    float ps[4];
    #pragma unroll
    for (int r = 0; r < 4; ++r) ps[r] = 0.f;
    #pragma unroll
    for (int n = 0; n < 4; ++n)
      #pragma unroll
      for (int r = 0; r < 4; ++r) { float p = __expf(s[n][r] - mrow[r]); s[n][r] = p; ps[r] += p; }
    #pragma unroll
    for (int r = 0; r < 4; ++r) {
      ps[r] = row16_sum(ps[r]);
      ssum[r] = ssum[r] * sc[r] + ps[r];
    }
    #pragma unroll
    for (int n = 0; n < 4; ++n)
      #pragma unroll
      for (int r = 0; r < 4; ++r) accO[n][r] *= sc[r];

    // P -> wave-private LDS (acc layout) then re-read as A-frags
    #pragma unroll
    for (int n = 0; n < 4; ++n)
      #pragma unroll
      for (int r = 0; r < 4; ++r)
        PL[w][(lg * 4 + r) * 72 + n * 16 + lr] = f2bf(s[n][r]);

    short8 pa0 = *(const short8*)&PL[w][lr * 72 + lg * 8];
    short8 pa1 = *(const short8*)&PL[w][lr * 72 + 32 + lg * 8];
    #pragma unroll
    for (int n = 0; n < 4; ++n) {
      const char* vp = (const char*)Vs[cur] + (n * 16 + lr) * 128;
      short8 vb0 = *(const short8*)(vp + off0);
      short8 vb1 = *(const short8*)(vp + off1);
      accO[n] = __builtin_amdgcn_mfma_f32_16x16x32_bf16(pa0, vb0, accO[n], 0, 0, 0);
      accO[n] = __builtin_amdgcn_mfma_f32_16x16x32_bf16(pa1, vb1, accO[n], 0, 0, 0);
    }

    asm volatile("s_waitcnt lgkmcnt(0)" ::: "memory");  // my LDS reads of buf[cur] retired
    __builtin_amdgcn_s_barrier();                        // safe to overwrite buf[cur]
  };

  for (int kt2 = 0; kt2 < 16; kt2 += 2) {
    body(kt2,     bb0, bb1);
    body(kt2 + 1, bb1, bb0);
  }

  const int b = bh >> 4, h = bh & 15;
  #pragma unroll
  for (int n = 0; n < 4; ++n)
    #pragma unroll
    for (int r = 0; r < 4; ++r) {
      const int qrow = q0 + lg * 4 + r;
      AO[(size_t)(qrow * 8 + b) * 1024 + h * 64 + n * 16 + lr] = f2bf(accO[n][r] / ssum[r]);
    }
}

// ---------------- LayerNorm over E=1024, one row per wave ----------------
__global__ __launch_bounds__(256) void ln_fwd(
    const short* __restrict__ X, const float* __restrict__ g,
    const float* __restrict__ be, short* __restrict__ Y)
{
  const int w = threadIdx.x >> 6, lane = threadIdx.x & 63;
  const int row = blockIdx.x * 4 + w;
  const short* xp = X + (size_t)row * 1024 + lane * 16;
  short8 a = *(const short8*)xp;
  short8 b = *(const short8*)(xp + 8);
  float f[16];
  #pragma unroll
  for (int j = 0; j < 8; ++j) { f[j] = bf2f(a[j]); f[8 + j] = bf2f(b[j]); }
  float sum = 0.f, sq = 0.f;
  #pragma unroll
  for (int j = 0; j < 16; ++j) { sum += f[j]; sq += f[j] * f[j]; }
  #pragma unroll
  for (int msk = 32; msk >= 1; msk >>= 1) { sum += __shfl_xor(sum, msk); sq += __shfl_xor(sq, msk); }
  const float mu = sum * (1.f / 1024.f);
  const float var = sq * (1.f / 1024.f) - mu * mu;
  const float rs = rsqrtf(var + 1e-5f);
  const int cb = lane * 16;
  short8 o0, o1;
  #pragma unroll
  for (int j = 0; j < 8; ++j) {
    o0[j] = f2bf((f[j] - mu) * rs * g[cb + j] + be[cb + j]);
    o1[j] = f2bf((f[8 + j] - mu) * rs * g[cb + 8 + j] + be[cb + 8 + j]);
  }
  *(short8*)(Y + (size_t)row * 1024 + cb) = o0;
  *(short8*)(Y + (size_t)row * 1024 + cb + 8) = o1;
}

extern "C" void kernel_launch(void* const* d_in, const int* in_sizes, int n_in,
                              void* d_out, int out_size, void* d_ws, size_t ws_size,
                              hipStream_t stream) {
  (void)in_sizes; (void)n_in; (void)out_size; (void)ws_size;
  const float* query = (const float*)d_in[0];
  const float* bias  = (const float*)d_in[1];
  const float* Wq    = (const float*)d_in[2];
  const float* bq    = (const float*)d_in[3];
  const float* Wk    = (const float*)d_in[4];
  const float* Wv    = (const float*)d_in[5];
  const float* bv    = (const float*)d_in[6];
  const float* Wo    = (const float*)d_in[7];
  const float* bo    = (const float*)d_in[8];
  const float* lng   = (const float*)d_in[9];
  const float* lnb   = (const float*)d_in[10];
  float* out = (float*)d_out;
  char* ws = (char*)d_ws;

  // workspace layout (72 MB total, with lifetime reuse)
  short* Wbf = (short*)ws;                     // 4x[1024x1024] bf16: 8 MB (q,k,v,o)
  short* Xbf = (short*)(ws + (8u << 20));      // [8192,1024] bf16: 16 MB
  short* Qbf = (short*)(ws + (24u << 20));     // [128,1024,64] bf16: 16 MB
  short* Kbf = (short*)(ws + (40u << 20));
  short* Vbf = (short*)(ws + (56u << 20));     // VT layout [128,64,1024]; ends at 72 MB
  short* AO  = Xbf;                            // reuse: X dead after QKV proj
  short* Ybf = Qbf;                            // reuse: Q dead after attention

  cvt_bf16<<<4096, 256, 0, stream>>>(query, Xbf, 1048576);
  cvt_bf16<<<512, 256, 0, stream>>>(Wq, Wbf,           131072);
  cvt_bf16<<<512, 256, 0, stream>>>(Wk, Wbf + 1048576, 131072);
  cvt_bf16<<<512, 256, 0, stream>>>(Wv, Wbf + 2097152, 131072);
  cvt_bf16<<<512, 256, 0, stream>>>(Wo, Wbf + 3145728, 131072);

  // DIAGNOSTIC ROUND: gemm<0> x4 reps, gemm<1> x12 reps (idempotent) so both
  // exceed the ~320us harness fills and surface in rocprof top-5 with counters.
  gemm_bt<0, 4><<<dim3(32, 24), 512, 0, stream>>>(Xbf, Wbf, bq, bv, Qbf, Kbf, Vbf, nullptr);
  attn_fwd<<<1024, 512, 0, stream>>>(Qbf, Kbf, Vbf, bias, AO);
  ln_fwd<<<2048, 256, 0, stream>>>(AO, lng, lnb, Ybf);
  gemm_bt<1, 12><<<dim3(32, 8), 512, 0, stream>>>(Ybf, Wbf + 3145728, bo, nullptr, nullptr, nullptr, nullptr, out);
}

// Round 16
// 279.811 us; speedup vs baseline: 2.4223x; 2.4223x over previous
//
#include <hip/hip_runtime.h>
#include <cstdint>
#include <cstddef>

typedef __attribute__((ext_vector_type(8))) short short8;
typedef __attribute__((ext_vector_type(4))) float f32x4;

#define DEV static __device__ __forceinline__

DEV float bf2f(short s) {
  union { unsigned u; float f; } c; c.u = ((unsigned)(unsigned short)s) << 16; return c.f;
}
DEV short f2bf(float f) {
  union { float f; unsigned u; } c; c.f = f;
  unsigned r = c.u + 0x7FFFu + ((c.u >> 16) & 1u);
  return (short)(r >> 16);
}

DEV void gload_lds16(const void* g, void* l) {
  __builtin_amdgcn_global_load_lds((const __attribute__((address_space(1))) void*)g,
                                   (__attribute__((address_space(3))) void*)l, 16, 0, 0);
}

// 16-lane-row reductions via DPP (VALU pipe, not DS): xor1, xor2, half-mirror, mirror
#define DPP_STEP(v, ctrl, OP) { \
  int _t = __builtin_amdgcn_update_dpp( \
      __builtin_bit_cast(int, v), __builtin_bit_cast(int, v), ctrl, 0xF, 0xF, true); \
  v = OP(v, __builtin_bit_cast(float, _t)); }
DEV float row16_max(float v) {
  DPP_STEP(v, 0xB1, fmaxf)   // quad_perm [1,0,3,2] = xor1
  DPP_STEP(v, 0x4E, fmaxf)   // quad_perm [2,3,0,1] = xor2
  DPP_STEP(v, 0x141, fmaxf)  // row_half_mirror
  DPP_STEP(v, 0x140, fmaxf)  // row_mirror
  return v;
}
DEV float fadd2(float a, float b) { return a + b; }
DEV float row16_sum(float v) {
  DPP_STEP(v, 0xB1, fadd2)
  DPP_STEP(v, 0x4E, fadd2)
  DPP_STEP(v, 0x141, fadd2)
  DPP_STEP(v, 0x140, fadd2)
  return v;
}

// ---------------- fp32 -> bf16 convert, 8 elems/thread ----------------
__global__ __launch_bounds__(256) void cvt_bf16(const float* __restrict__ s,
                                                short* __restrict__ d, int n8) {
  int i = blockIdx.x * 256 + threadIdx.x;
  if (i >= n8) return;
  const float4* sp = (const float4*)s + (size_t)i * 2;
  float4 a = sp[0], b = sp[1];
  short8 o;
  o[0] = f2bf(a.x); o[1] = f2bf(a.y); o[2] = f2bf(a.z); o[3] = f2bf(a.w);
  o[4] = f2bf(b.x); o[5] = f2bf(b.y); o[6] = f2bf(b.z); o[7] = f2bf(b.w);
  *((short8*)d + i) = o;
}

// ---------------- GEMM: C[m][n] = sum_k A[m][k] * W[n][k] (+bias) ----------------
// R13 structure (best known): 256x128 tile, BK=64, 8 waves (4Mx2N; per-wave
// 64x64), TRIPLE-buffered LDS (3 x 48 KB). Top-of-tile vmcnt(6) -> 2 phases
// of {ds_read frags + issue 3 staging loads for t+2 -> barrier -> setprio(1)
// -> 16 MFMA -> setprio(0) -> barrier}. Counted vmcnt, never 0 mid-loop.
// LDS XOR-swizzle key (row&7)<<4, both-sides (rule #21), bank-balanced b128.
// Grid: MODE 0 (32, 24) = 768 = 3 exact rounds; MODE 1 (32, 8) = 1 round.
template<int MODE>
__global__ __launch_bounds__(512) void gemm_bt(
    const short* __restrict__ A, const short* __restrict__ W,
    const float* __restrict__ biasA, const float* __restrict__ biasB,
    short* __restrict__ Oq, short* __restrict__ Ok, short* __restrict__ Ov,
    float* __restrict__ Of)
{
  __shared__ char SM[147456];  // slot s at s*49152: A [0,32K) + B [32K,48K)
  const int tid = threadIdx.x, w = tid >> 6, lane = tid & 63;
  const int lr = lane & 15, lg = lane >> 4;
  const int m0 = blockIdx.x * 256;
  int mat = 0, n0;
  const short* Wm;
  if (MODE == 0) { mat = blockIdx.y >> 3; n0 = (blockIdx.y & 7) * 128; Wm = W + (size_t)mat * 1048576; }
  else           { n0 = blockIdx.y * 128; Wm = W; }
  const int wr = (w >> 1) * 64, wc = (w & 1) * 64;   // wave tile: 64(M) x 64(N)

  f32x4 acc[4][4];
  const f32x4 fz = {0.f, 0.f, 0.f, 0.f};
  #pragma unroll
  for (int i = 0; i < 4; ++i)
    #pragma unroll
    for (int j = 0; j < 4; ++j) acc[i][j] = fz;

  // stage one half (3 loads/thread: 2 A + 1 B) of K-tile t into slot.
  auto stageHalf = [&](int t, int slot, int half) {
    const size_t kb = (size_t)t * 128;           // 64 cols * 2B
    char* Ad = SM + slot * 49152;
    char* Bd = Ad + 32768;
    #pragma unroll
    for (int i = 0; i < 2; ++i) {
      const int idx2 = (half * 2 + i) * 512 + tid;         // 0..2047
      const int r = idx2 >> 3, c16 = idx2 & 7;
      const int cs = (c16 ^ (r & 7)) << 4;
      gload_lds16((const char*)A + (size_t)(m0 + r) * 2048 + kb + cs, Ad + idx2 * 16);
    }
    {
      const int idx2 = half * 512 + tid;                   // 0..1023
      const int r = idx2 >> 3, c16 = idx2 & 7;
      const int cs = (c16 ^ (r & 7)) << 4;
      gload_lds16((const char*)Wm + (size_t)(n0 + r) * 2048 + kb + cs, Bd + idx2 * 16);
    }
  };

  // prologue: tiles 0 (slot 0) and 1 (slot 1) fully issued, 12 loads in flight
  stageHalf(0, 0, 0); stageHalf(0, 0, 1);
  stageHalf(1, 1, 0); stageHalf(1, 1, 1);

  int slot = 0;
  for (int t = 0; t < 16; ++t) {
    if (t < 15) asm volatile("s_waitcnt vmcnt(6)" ::: "memory");
    else        asm volatile("s_waitcnt vmcnt(0)" ::: "memory");
    __builtin_amdgcn_s_barrier();

    const char* Asl = SM + slot * 49152;
    const char* Bsl = Asl + 32768;
    const int slot2 = (slot == 0) ? 2 : slot - 1;          // (t+2)%3

    #pragma unroll
    for (int ks = 0; ks < 2; ++ks) {
      short8 af[4], bf[4];
      #pragma unroll
      for (int nr = 0; nr < 4; ++nr) {
        const int row = wc + nr * 16 + lr;
        bf[nr] = *(const short8*)(Bsl + row * 128 + ((ks * 64 + lg * 16) ^ ((row & 7) << 4)));
      }
      #pragma unroll
      for (int mr = 0; mr < 4; ++mr) {
        const int row = wr + mr * 16 + lr;
        af[mr] = *(const short8*)(Asl + row * 128 + ((ks * 64 + lg * 16) ^ ((row & 7) << 4)));
      }
      if (t < 14) stageHalf(t + 2, slot2, ks);             // 3 loads ride across phases
      __builtin_amdgcn_s_barrier();
      __builtin_amdgcn_s_setprio(1);
      #pragma unroll
      for (int mr = 0; mr < 4; ++mr)
        #pragma unroll
        for (int nr = 0; nr < 4; ++nr)
          acc[mr][nr] = __builtin_amdgcn_mfma_f32_16x16x32_bf16(af[mr], bf[nr], acc[mr][nr], 0, 0, 0);
      __builtin_amdgcn_s_setprio(0);
      __builtin_amdgcn_s_barrier();
    }
    slot = (slot == 2) ? 0 : slot + 1;
  }

  if (MODE == 0 && mat == 2) {
    // V epilogue: per 64-col half h2, transpose 256m x 64n through TB,
    // store 64B-contiguous s-runs into VT[bh][dd][s].
    short* TB = (short*)SM;                      // 256*68*2 = 34816 B
    #pragma unroll
    for (int h2 = 0; h2 < 2; ++h2) {
      __syncthreads();
      if ((w & 1) == h2) {                       // 4 waves own this n-half
        #pragma unroll
        for (int mr = 0; mr < 4; ++mr)
          #pragma unroll
          for (int nr = 0; nr < 4; ++nr)
            #pragma unroll
            for (int r = 0; r < 4; ++r) {
              const int ml = wr + mr * 16 + lg * 4 + r;
              const int nl = nr * 16 + lr;
              TB[ml * 68 + nl] = f2bf(acc[mr][nr][r] + biasB[n0 + h2 * 64 + nl]);
            }
      }
      __syncthreads();
      const int hh = (n0 >> 6) + h2;             // global head
      const int dd = tid & 63, b = tid >> 6;     // 64 dd x 8 b = 512 threads
      short tmp[32];
      #pragma unroll
      for (int j = 0; j < 32; ++j) tmp[j] = TB[(j * 8 + b) * 68 + dd];
      const size_t base = (size_t)(b * 16 + hh) * 65536 + (size_t)dd * 1024 + (m0 >> 3);
      #pragma unroll
      for (int j = 0; j < 4; ++j)
        *(short8*)(Ov + base + j * 8) = *(short8*)(tmp + j * 8);
    }
    return;
  }

  #pragma unroll
  for (int mr = 0; mr < 4; ++mr)
  #pragma unroll
  for (int nr = 0; nr < 4; ++nr)
  #pragma unroll
  for (int r = 0; r < 4; ++r) {
    const int mrow = m0 + wr + mr * 16 + lg * 4 + r;   // C row = (l>>4)*4+r  [m89]
    const int ncol = n0 + wc + nr * 16 + lr;           // C col = l&15
    float v = acc[mr][nr][r];
    if (MODE == 0) {
      const int s = mrow >> 3, b = mrow & 7, h = ncol >> 6, dd = ncol & 63;
      const size_t base = (size_t)(b * 16 + h) * 65536;
      if (mat == 0)      Oq[base + (size_t)s * 64 + dd] = f2bf((v + biasA[ncol]) * 0.125f);
      else               Ok[base + (size_t)s * 64 + dd] = f2bf(v);
    } else {
      Of[(size_t)mrow * 1024 + ncol] = v + biasA[ncol];
    }
  }
}

// ---------------- attention ----------------
// R16: 8 waves / 128 q-rows per block, one head; 16 KV steps.
// (1) K/V in THREE rotating LDS slots -> the end-of-step lgkmcnt+barrier is
//     deleted (write at step kt targets slot (kt+2)%3, two steps from its
//     last reader; the single top barrier bounds wave drift to <1 step).
// (2) Bias register double-buffer with MID-STEP fill: bb[kt&1] is consumed by
//     the bias-add, then refilled with bias(kt+2) -> 1.5-step runway.
// (3) kv issued before bias; top wait is uniform vmcnt(18) = drains exactly
//     {bias(kt), kv(kt)}, leaving {bias(kt+1), kv(kt+1)} in flight.
DEV void stage_kv(const char* Kg, const char* Vg, int kt,
                  short* ksb, short* vsb, int tid) {
  const int L = tid * 16;            // 512 threads x 16B = 8 KB tile
  const int row = L >> 7, c = L & 127;
  const int cs = c ^ ((row & 7) << 4);
  gload_lds16(Kg + (size_t)kt * 8192 + row * 128 + cs, (char*)ksb + L);
  gload_lds16(Vg + (size_t)row * 2048 + (size_t)kt * 128 + cs, (char*)vsb + L);
}

__global__ __launch_bounds__(512) void attn_fwd(
    const short* __restrict__ Q, const short* __restrict__ K,
    const short* __restrict__ VT, const float* __restrict__ bias,
    short* __restrict__ AO)
{
  __shared__ short Ks[3][4096];     // [s=64][d=64] bf16, swizzled      (24 KB)
  __shared__ short Vs[3][4096];     // [d=64][s=64] bf16, swizzled      (24 KB)
  __shared__ short PL[8][16 * 72];  // per-wave P strip, padded         (18 KB)
  const int tid = threadIdx.x, w = tid >> 6, lane = tid & 63;
  const int lr = lane & 15, lg = lane >> 4;
  // XCD-chunked swizzle: XCD x gets heads [x*16,(x+1)*16); 8 blocks/head
  const int bid = blockIdx.x;
  const int L = (bid & 7) * 128 + (bid >> 3);
  const int bh = L >> 3, qb = L & 7;
  const int q0 = qb * 128 + w * 16;

  const char* Kg = (const char*)K  + ((size_t)bh << 17);
  const char* Vg = (const char*)VT + ((size_t)bh << 17);
  const short* Qh = Q + ((size_t)bh << 16);
  // per-lane bias base: row (q0+lg*4), col lr
  const float* Bw = bias + ((size_t)bh << 20) + (size_t)(q0 + lg * 4) * 1024 + lr;

  const short8 qf0 = *(const short8*)(Qh + (q0 + lr) * 64 + lg * 8);
  const short8 qf1 = *(const short8*)(Qh + (q0 + lr) * 64 + 32 + lg * 8);

  // swizzled read offsets: row-dependent key is (lr&7) for row = n*16+lr
  const int S = (lr & 7) << 4;
  const int off0 = (lg * 16) ^ S;
  const int off1 = (64 + lg * 16) ^ S;

  const f32x4 fz = {0.f, 0.f, 0.f, 0.f};
  f32x4 accO[4] = {fz, fz, fz, fz};
  float mrow[4] = {-3e30f, -3e30f, -3e30f, -3e30f};
  float ssum[4] = {0.f, 0.f, 0.f, 0.f};

  // prologue: kv(0) FIRST, then bias(0), bias(1). vmcnt(16) drains kv0+bias0,
  // bias1 rides.
  float bb0[4][4], bb1[4][4];
  stage_kv(Kg, Vg, 0, Ks[0], Vs[0], tid);
  #pragma unroll
  for (int n = 0; n < 4; ++n)
    #pragma unroll
    for (int r = 0; r < 4; ++r)
      bb0[n][r] = Bw[(size_t)r * 1024 + n * 16];
  #pragma unroll
  for (int n = 0; n < 4; ++n)
    #pragma unroll
    for (int r = 0; r < 4; ++r)
      bb1[n][r] = Bw[(size_t)r * 1024 + 64 + n * 16];
  asm volatile("s_waitcnt vmcnt(16)" ::: "memory");
  __builtin_amdgcn_s_barrier();

  auto body = [&](int kt, float (&bbc)[4][4]) {
    // kv for NEXT step into rotating slot (kt+1)%3 (1-deep pipeline)
    if (kt <= 14) {
      const int sl = (kt + 1) % 3;
      stage_kv(Kg, Vg, kt + 1, Ks[sl], Vs[sl], tid);
    }
    __builtin_amdgcn_sched_barrier(0);
    // drains exactly {bias(kt), kv(kt)}; {bias(kt+1), kv(kt+1)} stay in flight
    if (kt <= 14) asm volatile("s_waitcnt vmcnt(18)" ::: "memory");
    else          asm volatile("s_waitcnt vmcnt(0)" ::: "memory");
    __builtin_amdgcn_s_barrier();   // the ONLY barrier per step

    const int cs3 = kt % 3;
    // S = Q*K^T from swizzled Ks
    f32x4 s[4];
    #pragma unroll
    for (int n = 0; n < 4; ++n) {
      const char* kp = (const char*)Ks[cs3] + (n * 16 + lr) * 128;
      short8 kf0 = *(const short8*)(kp + off0);
      short8 kf1 = *(const short8*)(kp + off1);
      f32x4 z = fz;
      z    = __builtin_amdgcn_mfma_f32_16x16x32_bf16(qf0, kf0, z, 0, 0, 0);
      s[n] = __builtin_amdgcn_mfma_f32_16x16x32_bf16(qf1, kf1, z, 0, 0, 0);
    }
    #pragma unroll
    for (int n = 0; n < 4; ++n)
      #pragma unroll
      for (int r = 0; r < 4; ++r) s[n][r] += bbc[n][r];

    // mid-step bias refill: bbc is dead now; fill it with bias(kt+2)
    if (kt <= 13) {
      #pragma unroll
      for (int n = 0; n < 4; ++n)
        #pragma unroll
        for (int r = 0; r < 4; ++r)
          bbc[n][r] = Bw[(size_t)r * 1024 + (kt + 2) * 64 + n * 16];
      __builtin_amdgcn_sched_barrier(0);
    }

    // online softmax; 16-lane row reduce via DPP (VALU pipe)
    float sc[4];
    #pragma unroll
    for (int r = 0; r < 4; ++r) {
      float t = fmaxf(fmaxf(s[0][r], s[1][r]), fmaxf(s[2][r], s[3][r]));
      t = row16_max(t);
      float mn = fmaxf(mrow[r], t);
      sc[r] = __expf(mrow[r] - mn);
      mrow[r] = mn;
    }
    float ps[4];
    #pragma unroll
    for (int r = 0; r < 4; ++r) ps[r] = 0.f;
    #pragma unroll
    for (int n = 0; n < 4; ++n)
      #pragma unroll
      for (int r = 0; r < 4; ++r) { float p = __expf(s[n][r] - mrow[r]); s[n][r] = p; ps[r] += p; }
    #pragma unroll
    for (int r = 0; r < 4; ++r) {
      ps[r] = row16_sum(ps[r]);
      ssum[r] = ssum[r] * sc[r] + ps[r];
    }
    #pragma unroll
    for (int n = 0; n < 4; ++n)
      #pragma unroll
      for (int r = 0; r < 4; ++r) accO[n][r] *= sc[r];

    // P -> wave-private LDS (acc layout) then re-read as A-frags (program order)
    #pragma unroll
    for (int n = 0; n < 4; ++n)
      #pragma unroll
      for (int r = 0; r < 4; ++r)
        PL[w][(lg * 4 + r) * 72 + n * 16 + lr] = f2bf(s[n][r]);

    short8 pa0 = *(const short8*)&PL[w][lr * 72 + lg * 8];
    short8 pa1 = *(const short8*)&PL[w][lr * 72 + 32 + lg * 8];
    #pragma unroll
    for (int n = 0; n < 4; ++n) {
      const char* vp = (const char*)Vs[cs3] + (n * 16 + lr) * 128;
      short8 vb0 = *(const short8*)(vp + off0);
      short8 vb1 = *(const short8*)(vp + off1);
      accO[n] = __builtin_amdgcn_mfma_f32_16x16x32_bf16(pa0, vb0, accO[n], 0, 0, 0);
      accO[n] = __builtin_amdgcn_mfma_f32_16x16x32_bf16(pa1, vb1, accO[n], 0, 0, 0);
    }
    // no end-of-step barrier: 3-slot rotation makes the next write target a
    // slot untouched since step kt-1 (all waves past the top barrier).
  };

  for (int kt2 = 0; kt2 < 16; kt2 += 2) {
    body(kt2,     bb0);
    body(kt2 + 1, bb1);
  }

  const int b = bh >> 4, h = bh & 15;
  #pragma unroll
  for (int n = 0; n < 4; ++n)
    #pragma unroll
    for (int r = 0; r < 4; ++r) {
      const int qrow = q0 + lg * 4 + r;
      AO[(size_t)(qrow * 8 + b) * 1024 + h * 64 + n * 16 + lr] = f2bf(accO[n][r] / ssum[r]);
    }
}

// ---------------- LayerNorm over E=1024, one row per wave ----------------
__global__ __launch_bounds__(256) void ln_fwd(
    const short* __restrict__ X, const float* __restrict__ g,
    const float* __restrict__ be, short* __restrict__ Y)
{
  const int w = threadIdx.x >> 6, lane = threadIdx.x & 63;
  const int row = blockIdx.x * 4 + w;
  const short* xp = X + (size_t)row * 1024 + lane * 16;
  short8 a = *(const short8*)xp;
  short8 b = *(const short8*)(xp + 8);
  float f[16];
  #pragma unroll
  for (int j = 0; j < 8; ++j) { f[j] = bf2f(a[j]); f[8 + j] = bf2f(b[j]); }
  float sum = 0.f, sq = 0.f;
  #pragma unroll
  for (int j = 0; j < 16; ++j) { sum += f[j]; sq += f[j] * f[j]; }
  #pragma unroll
  for (int msk = 32; msk >= 1; msk >>= 1) { sum += __shfl_xor(sum, msk); sq += __shfl_xor(sq, msk); }
  const float mu = sum * (1.f / 1024.f);
  const float var = sq * (1.f / 1024.f) - mu * mu;
  const float rs = rsqrtf(var + 1e-5f);
  const int cb = lane * 16;
  short8 o0, o1;
  #pragma unroll
  for (int j = 0; j < 8; ++j) {
    o0[j] = f2bf((f[j] - mu) * rs * g[cb + j] + be[cb + j]);
    o1[j] = f2bf((f[8 + j] - mu) * rs * g[cb + 8 + j] + be[cb + 8 + j]);
  }
  *(short8*)(Y + (size_t)row * 1024 + cb) = o0;
  *(short8*)(Y + (size_t)row * 1024 + cb + 8) = o1;
}

extern "C" void kernel_launch(void* const* d_in, const int* in_sizes, int n_in,
                              void* d_out, int out_size, void* d_ws, size_t ws_size,
                              hipStream_t stream) {
  (void)in_sizes; (void)n_in; (void)out_size; (void)ws_size;
  const float* query = (const float*)d_in[0];
  const float* bias  = (const float*)d_in[1];
  const float* Wq    = (const float*)d_in[2];
  const float* bq    = (const float*)d_in[3];
  const float* Wk    = (const float*)d_in[4];
  const float* Wv    = (const float*)d_in[5];
  const float* bv    = (const float*)d_in[6];
  const float* Wo    = (const float*)d_in[7];
  const float* bo    = (const float*)d_in[8];
  const float* lng   = (const float*)d_in[9];
  const float* lnb   = (const float*)d_in[10];
  float* out = (float*)d_out;
  char* ws = (char*)d_ws;

  // workspace layout (72 MB total, with lifetime reuse)
  short* Wbf = (short*)ws;                     // 4x[1024x1024] bf16: 8 MB (q,k,v,o)
  short* Xbf = (short*)(ws + (8u << 20));      // [8192,1024] bf16: 16 MB
  short* Qbf = (short*)(ws + (24u << 20));     // [128,1024,64] bf16: 16 MB
  short* Kbf = (short*)(ws + (40u << 20));
  short* Vbf = (short*)(ws + (56u << 20));     // VT layout [128,64,1024]; ends at 72 MB
  short* AO  = Xbf;                            // reuse: X dead after QKV proj
  short* Ybf = Qbf;                            // reuse: Q dead after attention

  cvt_bf16<<<4096, 256, 0, stream>>>(query, Xbf, 1048576);
  cvt_bf16<<<512, 256, 0, stream>>>(Wq, Wbf,           131072);
  cvt_bf16<<<512, 256, 0, stream>>>(Wk, Wbf + 1048576, 131072);
  cvt_bf16<<<512, 256, 0, stream>>>(Wv, Wbf + 2097152, 131072);
  cvt_bf16<<<512, 256, 0, stream>>>(Wo, Wbf + 3145728, 131072);

  gemm_bt<0><<<dim3(32, 24), 512, 0, stream>>>(Xbf, Wbf, bq, bv, Qbf, Kbf, Vbf, nullptr);
  attn_fwd<<<1024, 512, 0, stream>>>(Qbf, Kbf, Vbf, bias, AO);
  ln_fwd<<<2048, 256, 0, stream>>>(AO, lng, lnb, Ybf);
  gemm_bt<1><<<dim3(32, 8), 512, 0, stream>>>(Ybf, Wbf + 3145728, bo, nullptr, nullptr, nullptr, nullptr, out);
}

// Round 17
// 269.021 us; speedup vs baseline: 2.5195x; 1.0401x over previous
//
#include <hip/hip_runtime.h>
#include <cstdint>
#include <cstddef>

typedef __attribute__((ext_vector_type(8))) short short8;
typedef __attribute__((ext_vector_type(4))) float f32x4;

#define DEV static __device__ __forceinline__

DEV float bf2f(short s) {
  union { unsigned u; float f; } c; c.u = ((unsigned)(unsigned short)s) << 16; return c.f;
}
DEV short f2bf(float f) {
  union { float f; unsigned u; } c; c.f = f;
  unsigned r = c.u + 0x7FFFu + ((c.u >> 16) & 1u);
  return (short)(r >> 16);
}

DEV void gload_lds16(const void* g, void* l) {
  __builtin_amdgcn_global_load_lds((const __attribute__((address_space(1))) void*)g,
                                   (__attribute__((address_space(3))) void*)l, 16, 0, 0);
}

// 16-lane-row reductions via DPP (VALU pipe, not DS): xor1, xor2, half-mirror, mirror
#define DPP_STEP(v, ctrl, OP) { \
  int _t = __builtin_amdgcn_update_dpp( \
      __builtin_bit_cast(int, v), __builtin_bit_cast(int, v), ctrl, 0xF, 0xF, true); \
  v = OP(v, __builtin_bit_cast(float, _t)); }
DEV float row16_max(float v) {
  DPP_STEP(v, 0xB1, fmaxf)   // quad_perm [1,0,3,2] = xor1
  DPP_STEP(v, 0x4E, fmaxf)   // quad_perm [2,3,0,1] = xor2
  DPP_STEP(v, 0x141, fmaxf)  // row_half_mirror
  DPP_STEP(v, 0x140, fmaxf)  // row_mirror
  return v;
}
DEV float fadd2(float a, float b) { return a + b; }
DEV float row16_sum(float v) {
  DPP_STEP(v, 0xB1, fadd2)
  DPP_STEP(v, 0x4E, fadd2)
  DPP_STEP(v, 0x141, fadd2)
  DPP_STEP(v, 0x140, fadd2)
  return v;
}

// ---------------- fp32 -> bf16 convert, ALL inputs in ONE dispatch ----------------
// Segments (in units of 8-elem groups): [0, 1048576) query -> Xbf;
// [1048576 + m*131072, ...) weight m -> Wbf + m*1048576. Segment boundaries are
// multiples of 131072 >= blockDim, so the branch is block-uniform.
__global__ __launch_bounds__(256) void cvt_all(
    const float* __restrict__ query, const float* __restrict__ Wq,
    const float* __restrict__ Wk, const float* __restrict__ Wv,
    const float* __restrict__ Wo, short* __restrict__ Xbf,
    short* __restrict__ Wbf) {
  const int i = blockIdx.x * 256 + threadIdx.x;
  const float* src;
  short* dst;
  int off;
  if (i < 1048576) {
    src = query; dst = Xbf; off = i;
  } else {
    const int j = i - 1048576;
    const int m = j >> 17;           // 131072 = 1<<17
    off = j & 131071;
    src = (m == 0) ? Wq : (m == 1) ? Wk : (m == 2) ? Wv : Wo;
    dst = Wbf + ((size_t)m << 20);
  }
  const float4* sp = (const float4*)src + (size_t)off * 2;
  float4 a = sp[0], b = sp[1];
  short8 o;
  o[0] = f2bf(a.x); o[1] = f2bf(a.y); o[2] = f2bf(a.z); o[3] = f2bf(a.w);
  o[4] = f2bf(b.x); o[5] = f2bf(b.y); o[6] = f2bf(b.z); o[7] = f2bf(b.w);
  *((short8*)dst + off) = o;
}

// ---------------- GEMM: C[m][n] = sum_k A[m][k] * W[n][k] (+bias) ----------------
// R13 structure (best known): 256x128 tile, BK=64, 8 waves (4Mx2N; per-wave
// 64x64), TRIPLE-buffered LDS (3 x 48 KB). Top-of-tile vmcnt(6) -> 2 phases
// of {ds_read frags + issue 3 staging loads for t+2 -> barrier -> setprio(1)
// -> 16 MFMA -> setprio(0) -> barrier}. Counted vmcnt, never 0 mid-loop.
// LDS XOR-swizzle key (row&7)<<4, both-sides (rule #21), bank-balanced b128.
// Grid: MODE 0 (32, 24) = 768 = 3 exact rounds; MODE 1 (32, 8) = 1 round.
template<int MODE>
__global__ __launch_bounds__(512) void gemm_bt(
    const short* __restrict__ A, const short* __restrict__ W,
    const float* __restrict__ biasA, const float* __restrict__ biasB,
    short* __restrict__ Oq, short* __restrict__ Ok, short* __restrict__ Ov,
    float* __restrict__ Of)
{
  __shared__ char SM[147456];  // slot s at s*49152: A [0,32K) + B [32K,48K)
  const int tid = threadIdx.x, w = tid >> 6, lane = tid & 63;
  const int lr = lane & 15, lg = lane >> 4;
  const int m0 = blockIdx.x * 256;
  int mat = 0, n0;
  const short* Wm;
  if (MODE == 0) { mat = blockIdx.y >> 3; n0 = (blockIdx.y & 7) * 128; Wm = W + (size_t)mat * 1048576; }
  else           { n0 = blockIdx.y * 128; Wm = W; }
  const int wr = (w >> 1) * 64, wc = (w & 1) * 64;   // wave tile: 64(M) x 64(N)

  f32x4 acc[4][4];
  const f32x4 fz = {0.f, 0.f, 0.f, 0.f};
  #pragma unroll
  for (int i = 0; i < 4; ++i)
    #pragma unroll
    for (int j = 0; j < 4; ++j) acc[i][j] = fz;

  // stage one half (3 loads/thread: 2 A + 1 B) of K-tile t into slot.
  auto stageHalf = [&](int t, int slot, int half) {
    const size_t kb = (size_t)t * 128;           // 64 cols * 2B
    char* Ad = SM + slot * 49152;
    char* Bd = Ad + 32768;
    #pragma unroll
    for (int i = 0; i < 2; ++i) {
      const int idx2 = (half * 2 + i) * 512 + tid;         // 0..2047
      const int r = idx2 >> 3, c16 = idx2 & 7;
      const int cs = (c16 ^ (r & 7)) << 4;
      gload_lds16((const char*)A + (size_t)(m0 + r) * 2048 + kb + cs, Ad + idx2 * 16);
    }
    {
      const int idx2 = half * 512 + tid;                   // 0..1023
      const int r = idx2 >> 3, c16 = idx2 & 7;
      const int cs = (c16 ^ (r & 7)) << 4;
      gload_lds16((const char*)Wm + (size_t)(n0 + r) * 2048 + kb + cs, Bd + idx2 * 16);
    }
  };

  // prologue: tiles 0 (slot 0) and 1 (slot 1) fully issued, 12 loads in flight
  stageHalf(0, 0, 0); stageHalf(0, 0, 1);
  stageHalf(1, 1, 0); stageHalf(1, 1, 1);

  int slot = 0;
  for (int t = 0; t < 16; ++t) {
    if (t < 15) asm volatile("s_waitcnt vmcnt(6)" ::: "memory");
    else        asm volatile("s_waitcnt vmcnt(0)" ::: "memory");
    __builtin_amdgcn_s_barrier();

    const char* Asl = SM + slot * 49152;
    const char* Bsl = Asl + 32768;
    const int slot2 = (slot == 0) ? 2 : slot - 1;          // (t+2)%3

    #pragma unroll
    for (int ks = 0; ks < 2; ++ks) {
      short8 af[4], bf[4];
      #pragma unroll
      for (int nr = 0; nr < 4; ++nr) {
        const int row = wc + nr * 16 + lr;
        bf[nr] = *(const short8*)(Bsl + row * 128 + ((ks * 64 + lg * 16) ^ ((row & 7) << 4)));
      }
      #pragma unroll
      for (int mr = 0; mr < 4; ++mr) {
        const int row = wr + mr * 16 + lr;
        af[mr] = *(const short8*)(Asl + row * 128 + ((ks * 64 + lg * 16) ^ ((row & 7) << 4)));
      }
      if (t < 14) stageHalf(t + 2, slot2, ks);             // 3 loads ride across phases
      __builtin_amdgcn_s_barrier();
      __builtin_amdgcn_s_setprio(1);
      #pragma unroll
      for (int mr = 0; mr < 4; ++mr)
        #pragma unroll
        for (int nr = 0; nr < 4; ++nr)
          acc[mr][nr] = __builtin_amdgcn_mfma_f32_16x16x32_bf16(af[mr], bf[nr], acc[mr][nr], 0, 0, 0);
      __builtin_amdgcn_s_setprio(0);
      __builtin_amdgcn_s_barrier();
    }
    slot = (slot == 2) ? 0 : slot + 1;
  }

  if (MODE == 0 && mat == 2) {
    // V epilogue: per 64-col half h2, transpose 256m x 64n through TB,
    // store 64B-contiguous s-runs into VT[bh][dd][s].
    short* TB = (short*)SM;                      // 256*68*2 = 34816 B
    #pragma unroll
    for (int h2 = 0; h2 < 2; ++h2) {
      __syncthreads();
      if ((w & 1) == h2) {                       // 4 waves own this n-half
        #pragma unroll
        for (int mr = 0; mr < 4; ++mr)
          #pragma unroll
          for (int nr = 0; nr < 4; ++nr)
            #pragma unroll
            for (int r = 0; r < 4; ++r) {
              const int ml = wr + mr * 16 + lg * 4 + r;
              const int nl = nr * 16 + lr;
              TB[ml * 68 + nl] = f2bf(acc[mr][nr][r] + biasB[n0 + h2 * 64 + nl]);
            }
      }
      __syncthreads();
      const int hh = (n0 >> 6) + h2;             // global head
      const int dd = tid & 63, b = tid >> 6;     // 64 dd x 8 b = 512 threads
      short tmp[32];
      #pragma unroll
      for (int j = 0; j < 32; ++j) tmp[j] = TB[(j * 8 + b) * 68 + dd];
      const size_t base = (size_t)(b * 16 + hh) * 65536 + (size_t)dd * 1024 + (m0 >> 3);
      #pragma unroll
      for (int j = 0; j < 4; ++j)
        *(short8*)(Ov + base + j * 8) = *(short8*)(tmp + j * 8);
    }
    return;
  }

  #pragma unroll
  for (int mr = 0; mr < 4; ++mr)
  #pragma unroll
  for (int nr = 0; nr < 4; ++nr)
  #pragma unroll
  for (int r = 0; r < 4; ++r) {
    const int mrow = m0 + wr + mr * 16 + lg * 4 + r;   // C row = (l>>4)*4+r  [m89]
    const int ncol = n0 + wc + nr * 16 + lr;           // C col = l&15
    float v = acc[mr][nr][r];
    if (MODE == 0) {
      const int s = mrow >> 3, b = mrow & 7, h = ncol >> 6, dd = ncol & 63;
      const size_t base = (size_t)(b * 16 + h) * 65536;
      if (mat == 0)      Oq[base + (size_t)s * 64 + dd] = f2bf((v + biasA[ncol]) * 0.125f);
      else               Ok[base + (size_t)s * 64 + dd] = f2bf(v);
    } else {
      Of[(size_t)mrow * 1024 + ncol] = v + biasA[ncol];
    }
  }
}

// ---------------- attention ----------------
// R7/R13 structure (best known): 8 waves / 128 q-rows per block, K/V LDS-staged
// with both-sides XOR swizzle, bias in register double-buffer, 1-iteration
// pipeline via counted vmcnt(18), DPP softmax.
DEV void stage_kv(const char* Kg, const char* Vg, int kt,
                  short* ksb, short* vsb, int tid) {
  const int L = tid * 16;            // 512 threads x 16B = 8 KB tile
  const int row = L >> 7, c = L & 127;
  const int cs = c ^ ((row & 7) << 4);
  gload_lds16(Kg + (size_t)kt * 8192 + row * 128 + cs, (char*)ksb + L);
  gload_lds16(Vg + (size_t)row * 2048 + (size_t)kt * 128 + cs, (char*)vsb + L);
}

__global__ __launch_bounds__(512) void attn_fwd(
    const short* __restrict__ Q, const short* __restrict__ K,
    const short* __restrict__ VT, const float* __restrict__ bias,
    short* __restrict__ AO)
{
  __shared__ short Ks[2][4096];     // [s=64][d=64] bf16, swizzled      (16 KB)
  __shared__ short Vs[2][4096];     // [d=64][s=64] bf16, swizzled      (16 KB)
  __shared__ short PL[8][16 * 72];  // per-wave P strip, padded         (18 KB)
  const int tid = threadIdx.x, w = tid >> 6, lane = tid & 63;
  const int lr = lane & 15, lg = lane >> 4;
  // XCD-chunked swizzle: XCD x gets heads [x*16,(x+1)*16); 8 blocks/head
  const int bid = blockIdx.x;
  const int L = (bid & 7) * 128 + (bid >> 3);
  const int bh = L >> 3, qb = L & 7;
  const int q0 = qb * 128 + w * 16;

  const char* Kg = (const char*)K  + ((size_t)bh << 17);
  const char* Vg = (const char*)VT + ((size_t)bh << 17);
  const short* Qh = Q + ((size_t)bh << 16);
  // per-lane bias base: row (q0+lg*4), col lr
  const float* Bw = bias + ((size_t)bh << 20) + (size_t)(q0 + lg * 4) * 1024 + lr;

  const short8 qf0 = *(const short8*)(Qh + (q0 + lr) * 64 + lg * 8);
  const short8 qf1 = *(const short8*)(Qh + (q0 + lr) * 64 + 32 + lg * 8);

  // swizzled read offsets: row-dependent key is (lr&7) for row = n*16+lr
  const int S = (lr & 7) << 4;
  const int off0 = (lg * 16) ^ S;
  const int off1 = (64 + lg * 16) ^ S;

  const f32x4 fz = {0.f, 0.f, 0.f, 0.f};
  f32x4 accO[4] = {fz, fz, fz, fz};
  float mrow[4] = {-3e30f, -3e30f, -3e30f, -3e30f};
  float ssum[4] = {0.f, 0.f, 0.f, 0.f};

  float bb0[4][4], bb1[4][4];
  #pragma unroll
  for (int n = 0; n < 4; ++n)
    #pragma unroll
    for (int r = 0; r < 4; ++r)
      bb0[n][r] = Bw[(size_t)r * 1024 + n * 16];
  stage_kv(Kg, Vg, 0, Ks[0], Vs[0], tid);
  asm volatile("s_waitcnt vmcnt(0)" ::: "memory");
  __builtin_amdgcn_s_barrier();

  auto body = [&](int kt, float (&bbc)[4][4], float (&bbn)[4][4]) {
    const int cur = kt & 1;
    if (kt < 15) {
      // bias prefetch for kt+1 into registers (dominant HBM stream)
      #pragma unroll
      for (int n = 0; n < 4; ++n)
        #pragma unroll
        for (int r = 0; r < 4; ++r)
          bbn[n][r] = Bw[(size_t)r * 1024 + (kt + 1) * 64 + n * 16];
      stage_kv(Kg, Vg, kt + 1, Ks[cur ^ 1], Vs[cur ^ 1], tid);
      __builtin_amdgcn_sched_barrier(0);   // pin prefetch issue before compute
      asm volatile("s_waitcnt vmcnt(18)" ::: "memory");  // drain tile kt (16 bias + 2 KV newer)
    } else {
      asm volatile("s_waitcnt vmcnt(0)" ::: "memory");
    }
    __builtin_amdgcn_s_barrier();   // buf[cur] complete for all waves

    // S = Q*K^T from swizzled Ks
    f32x4 s[4];
    #pragma unroll
    for (int n = 0; n < 4; ++n) {
      const char* kp = (const char*)Ks[cur] + (n * 16 + lr) * 128;
      short8 kf0 = *(const short8*)(kp + off0);
      short8 kf1 = *(const short8*)(kp + off1);
      f32x4 z = fz;
      z    = __builtin_amdgcn_mfma_f32_16x16x32_bf16(qf0, kf0, z, 0, 0, 0);
      s[n] = __builtin_amdgcn_mfma_f32_16x16x32_bf16(qf1, kf1, z, 0, 0, 0);
    }
    #pragma unroll
    for (int n = 0; n < 4; ++n)
      #pragma unroll
      for (int r = 0; r < 4; ++r) s[n][r] += bbc[n][r];

    // online softmax; 16-lane row reduce via DPP (VALU pipe)
    float sc[4];
    #pragma unroll
    for (int r = 0; r < 4; ++r) {
      float t = fmaxf(fmaxf(s[0][r], s[1][r]), fmaxf(s[2][r], s[3][r]));
      t = row16_max(t);
      float mn = fmaxf(mrow[r], t);
      sc[r] = __expf(mrow[r] - mn);
      mrow[r] = mn;
    }
    float ps[4];
    #pragma unroll
    for (int r = 0; r < 4; ++r) ps[r] = 0.f;
    #pragma unroll
    for (int n = 0; n < 4; ++n)
      #pragma unroll
      for (int r = 0; r < 4; ++r) { float p = __expf(s[n][r] - mrow[r]); s[n][r] = p; ps[r] += p; }
    #pragma unroll
    for (int r = 0; r < 4; ++r) {
      ps[r] = row16_sum(ps[r]);
      ssum[r] = ssum[r] * sc[r] + ps[r];
    }
    #pragma unroll
    for (int n = 0; n < 4; ++n)
      #pragma unroll
      for (int r = 0; r < 4; ++r) accO[n][r] *= sc[r];

    // P -> wave-private LDS (acc layout) then re-read as A-frags
    #pragma unroll
    for (int n = 0; n < 4; ++n)
      #pragma unroll
      for (int r = 0; r < 4; ++r)
        PL[w][(lg * 4 + r) * 72 + n * 16 + lr] = f2bf(s[n][r]);

    short8 pa0 = *(const short8*)&PL[w][lr * 72 + lg * 8];
    short8 pa1 = *(const short8*)&PL[w][lr * 72 + 32 + lg * 8];
    #pragma unroll
    for (int n = 0; n < 4; ++n) {
      const char* vp = (const char*)Vs[cur] + (n * 16 + lr) * 128;
      short8 vb0 = *(const short8*)(vp + off0);
      short8 vb1 = *(const short8*)(vp + off1);
      accO[n] = __builtin_amdgcn_mfma_f32_16x16x32_bf16(pa0, vb0, accO[n], 0, 0, 0);
      accO[n] = __builtin_amdgcn_mfma_f32_16x16x32_bf16(pa1, vb1, accO[n], 0, 0, 0);
    }

    asm volatile("s_waitcnt lgkmcnt(0)" ::: "memory");  // my LDS reads of buf[cur] retired
    __builtin_amdgcn_s_barrier();                        // safe to overwrite buf[cur]
  };

  for (int kt2 = 0; kt2 < 16; kt2 += 2) {
    body(kt2,     bb0, bb1);
    body(kt2 + 1, bb1, bb0);
  }

  const int b = bh >> 4, h = bh & 15;
  #pragma unroll
  for (int n = 0; n < 4; ++n)
    #pragma unroll
    for (int r = 0; r < 4; ++r) {
      const int qrow = q0 + lg * 4 + r;
      AO[(size_t)(qrow * 8 + b) * 1024 + h * 64 + n * 16 + lr] = f2bf(accO[n][r] / ssum[r]);
    }
}

// ---------------- LayerNorm over E=1024, one row per wave ----------------
__global__ __launch_bounds__(256) void ln_fwd(
    const short* __restrict__ X, const float* __restrict__ g,
    const float* __restrict__ be, short* __restrict__ Y)
{
  const int w = threadIdx.x >> 6, lane = threadIdx.x & 63;
  const int row = blockIdx.x * 4 + w;
  const short* xp = X + (size_t)row * 1024 + lane * 16;
  short8 a = *(const short8*)xp;
  short8 b = *(const short8*)(xp + 8);
  float f[16];
  #pragma unroll
  for (int j = 0; j < 8; ++j) { f[j] = bf2f(a[j]); f[8 + j] = bf2f(b[j]); }
  float sum = 0.f, sq = 0.f;
  #pragma unroll
  for (int j = 0; j < 16; ++j) { sum += f[j]; sq += f[j] * f[j]; }
  #pragma unroll
  for (int msk = 32; msk >= 1; msk >>= 1) { sum += __shfl_xor(sum, msk); sq += __shfl_xor(sq, msk); }
  const float mu = sum * (1.f / 1024.f);
  const float var = sq * (1.f / 1024.f) - mu * mu;
  const float rs = rsqrtf(var + 1e-5f);
  const int cb = lane * 16;
  short8 o0, o1;
  #pragma unroll
  for (int j = 0; j < 8; ++j) {
    o0[j] = f2bf((f[j] - mu) * rs * g[cb + j] + be[cb + j]);
    o1[j] = f2bf((f[8 + j] - mu) * rs * g[cb + 8 + j] + be[cb + 8 + j]);
  }
  *(short8*)(Y + (size_t)row * 1024 + cb) = o0;
  *(short8*)(Y + (size_t)row * 1024 + cb + 8) = o1;
}

extern "C" void kernel_launch(void* const* d_in, const int* in_sizes, int n_in,
                              void* d_out, int out_size, void* d_ws, size_t ws_size,
                              hipStream_t stream) {
  (void)in_sizes; (void)n_in; (void)out_size; (void)ws_size;
  const float* query = (const float*)d_in[0];
  const float* bias  = (const float*)d_in[1];
  const float* Wq    = (const float*)d_in[2];
  const float* bq    = (const float*)d_in[3];
  const float* Wk    = (const float*)d_in[4];
  const float* Wv    = (const float*)d_in[5];
  const float* bv    = (const float*)d_in[6];
  const float* Wo    = (const float*)d_in[7];
  const float* bo    = (const float*)d_in[8];
  const float* lng   = (const float*)d_in[9];
  const float* lnb   = (const float*)d_in[10];
  float* out = (float*)d_out;
  char* ws = (char*)d_ws;

  // workspace layout (72 MB total, with lifetime reuse)
  short* Wbf = (short*)ws;                     // 4x[1024x1024] bf16: 8 MB (q,k,v,o)
  short* Xbf = (short*)(ws + (8u << 20));      // [8192,1024] bf16: 16 MB
  short* Qbf = (short*)(ws + (24u << 20));     // [128,1024,64] bf16: 16 MB
  short* Kbf = (short*)(ws + (40u << 20));
  short* Vbf = (short*)(ws + (56u << 20));     // VT layout [128,64,1024]; ends at 72 MB
  short* AO  = Xbf;                            // reuse: X dead after QKV proj
  short* Ybf = Qbf;                            // reuse: Q dead after attention

  // ONE conversion dispatch for query + all 4 weights (was 5 dispatches)
  cvt_all<<<6144, 256, 0, stream>>>(query, Wq, Wk, Wv, Wo, Xbf, Wbf);

  gemm_bt<0><<<dim3(32, 24), 512, 0, stream>>>(Xbf, Wbf, bq, bv, Qbf, Kbf, Vbf, nullptr);
  attn_fwd<<<1024, 512, 0, stream>>>(Qbf, Kbf, Vbf, bias, AO);
  ln_fwd<<<2048, 256, 0, stream>>>(AO, lng, lnb, Ybf);
  gemm_bt<1><<<dim3(32, 8), 512, 0, stream>>>(Ybf, Wbf + 3145728, bo, nullptr, nullptr, nullptr, nullptr, out);
}